// Round 5
// baseline (1583.154 us; speedup 1.0000x reference)
//
#include <hip/hip_runtime.h>

// EP model, deviation-space formulation with Gram-matrix substitution.
// s_k = c_k + d_k, c = free forward chain (exact fixed point).
// e3 = beta*(c3-y); iter0: d3=-lr*e3, d2=-lr*e3@W2^T, d1=-lr*e3@P^T (P=W1@W2)
// iters 1..19 (G1=W1W1^T, G2=W2W2^T; all three updates independent):
//   d1' = (1-lr)d1 + lr*(d2@W1^T - d1@G1)
//   d2' = (1-lr)d2 + lr*(d1@W1 + d3@W2^T - d2@G2)
//   d3' = (1-lr-lr*b)d3 + lr*(d2@W2) - lr*e3
// final: r2* = d2 - d1@W1 ; r3* = d3 - d2@W2
// ep0 = -(1/b) x^T d1 ; ep1 = -(1/b)(c1+d1)^T r2* ; ep2 = -(1/b)(c2+d2)^T r3*
// loss = mean(e3^2)/b^2
//
// NT MFMA GEMM with concat-K regions; bf16 operands stored pre-swizzled
// (16B chunk c at c^(row&7) within each 128B window); global_load_lds
// (width 16) stages linearly; ds_read applies the same XOR.

typedef float f32x4 __attribute__((ext_vector_type(4)));
typedef __bf16 bf16x8 __attribute__((ext_vector_type(8)));
typedef unsigned short u16;
typedef unsigned int u32;

namespace {

constexpr float LR = 0.5f;
constexpr float BETA = 1e-3f;

__device__ inline void splitbf(float v, u16& h, u16& l) {
  __bf16 hb = (__bf16)v;
  float hf = (float)hb;
  __bf16 lb = (__bf16)(v - hf);
  h = __builtin_bit_cast(u16, hb);
  l = __builtin_bit_cast(u16, lb);
}
__device__ inline u32 pack2(u16 a, u16 b) { return (u32)a | ((u32)b << 16); }

__device__ inline f32x4 MF(bf16x8 a, bf16x8 b, f32x4 c) {
  return __builtin_amdgcn_mfma_f32_16x16x32_bf16(a, b, c, 0, 0, 0);
}

__device__ inline int swzc(int row, int col) {
  return (col & ~63) | ((((col >> 3) & 7) ^ (row & 7)) << 3) | (col & 7);
}

struct Region {
  const u16 *Ah, *Al, *Bh, *Bl;
  int kw, nks;  // row width (elements) and k-steps (kw/64)
};

struct GemmP {
  Region rg[3];
  const float *E0, *E1;
  float *of, *of2, *of3;
  u16 *oh, *ol, *oh2, *ol2;
  float alpha, c0, c1v;
  int N, ntn, role;
};

// ---------------------------------------------------------------------------
// NT MFMA GEMM, 64x64 tile, BK=64, 4 waves, global_load_lds, concat-K regions.
// C[m,n] = sum_regions sum_k A_r[m,k]*B_r[n,k]
// NP=2: (Ah+Al)*Bh ; NP=3: + Ah*Bl
// role 0: v = alpha*S + c0*E0 + c1v*E1 -> of?, (oh,ol?) swizzled-split
// role 1: e=BETA*(S-E0) -> of2 + (oh,ol); d=-LR*e -> of3 + (oh2,ol2)
// ---------------------------------------------------------------------------
template <int NP>
__global__ __launch_bounds__(256) void gemm_g(GemmP ca, GemmP cb, GemmP cc,
                                              GemmP cd, int nb0, int nb1,
                                              int nb2) {
  constexpr int NARR = NP + 1;
  constexpr int NCH = NARR * 2;
  __shared__ u16 lds[2][NARR][64 * 64];
  GemmP c;
  int b = blockIdx.x;
  if (b < nb0) c = ca;
  else if (b < nb1) { c = cb; b -= nb0; }
  else if (b < nb2) { c = cc; b -= nb1; }
  else { c = cd; b -= nb2; }
  const int tm = b / c.ntn, tn = b % c.ntn;
  const int tid = threadIdx.x, lane = tid & 63, w = tid >> 6;

  // ---- staging chunk geometry: chunk q -> array a=q>>1, row-block rb ----
  const int inrow = (lane & 7) << 4;
  int ro2048[NCH], ro1024[NCH], loffq[NCH];
#pragma unroll
  for (int q = 0; q < NCH; ++q) {
    const int a = q >> 1;
    const int rb = (q & 1) * 4 + w;
    const int row = ((a < 2) ? tm : tn) * 64 + rb * 8 + (lane >> 3);
    ro2048[q] = row * 2048 + inrow;
    ro1024[q] = row * 1024 + inrow;
    loffq[q] = a * 8192 + rb * 1024;
  }

  // ---- fragment read byte offsets ----
  const int wm = (w >> 1) << 5, wn = (w & 1) << 5;
  const int fr = lane & 15, fs = lane >> 4;
  int aoff[2][2], boff[2][2];
#pragma unroll
  for (int i = 0; i < 2; ++i)
#pragma unroll
    for (int kk = 0; kk < 2; ++kk) {
      const int ra = wm + i * 16 + fr;
      aoff[i][kk] = ra * 128 + ((((kk << 2) + fs) ^ (ra & 7)) << 4);
      const int rb2 = wn + i * 16 + fr;
      boff[i][kk] = rb2 * 128 + ((((kk << 2) + fs) ^ (rb2 & 7)) << 4);
    }

  const int rs1 = c.rg[0].nks;
  const int rs2 = rs1 + c.rg[1].nks;
  const int nk = rs2 + c.rg[2].nks;

  auto stage = [&](int s, int buf) {
    const int r = (s >= rs1) + (s >= rs2);
    const Region& rg = (r == 0) ? c.rg[0] : (r == 1) ? c.rg[1] : c.rg[2];
    const int local = s - ((r == 0) ? 0 : (r == 1) ? rs1 : rs2);
    const bool wide = (rg.kw == 1024);
    char* lb = (char*)&lds[buf][0][0];
#pragma unroll
    for (int q = 0; q < NCH; ++q) {
      const int a = q >> 1;
      const u16* base = (a == 0) ? rg.Ah : (a == 1) ? rg.Al
                        : (a == 2) ? rg.Bh : rg.Bl;
      const char* src = (const char*)base + (wide ? ro2048[q] : ro1024[q]) +
                        (size_t)local * 128;
      __builtin_amdgcn_global_load_lds(
          (const __attribute__((address_space(1))) unsigned int*)src,
          (__attribute__((address_space(3))) unsigned int*)(lb + loffq[q]), 16,
          0, 0);
    }
  };

  f32x4 acc[2][2] = {};
  stage(0, 0);
  __syncthreads();
  int cur = 0;
  for (int s = 0; s < nk; ++s) {
    if (s + 1 < nk) stage(s + 1, cur ^ 1);
    const char* rb = (const char*)&lds[cur][0][0];
    bf16x8 ah[2][2], al[2][2], bh[2][2], bl[2][2];
#pragma unroll
    for (int i = 0; i < 2; ++i)
#pragma unroll
      for (int kk = 0; kk < 2; ++kk) {
        ah[i][kk] = *(const bf16x8*)(rb + aoff[i][kk]);
        al[i][kk] = *(const bf16x8*)(rb + 8192 + aoff[i][kk]);
        bh[i][kk] = *(const bf16x8*)(rb + 16384 + boff[i][kk]);
        if (NP == 3) bl[i][kk] = *(const bf16x8*)(rb + 24576 + boff[i][kk]);
      }
#pragma unroll
    for (int kk = 0; kk < 2; ++kk)
#pragma unroll
      for (int i = 0; i < 2; ++i)
#pragma unroll
        for (int j = 0; j < 2; ++j) {
          acc[i][j] = MF(ah[i][kk], bh[j][kk], acc[i][j]);
          acc[i][j] = MF(al[i][kk], bh[j][kk], acc[i][j]);
          if (NP == 3) acc[i][j] = MF(ah[i][kk], bl[j][kk], acc[i][j]);
        }
    __syncthreads();
    cur ^= 1;
  }

  // ---- epilogue; C/D layout: col=lane&15, row=(lane>>4)*4+reg ----
  const int N = c.N;
#pragma unroll
  for (int i = 0; i < 2; ++i)
#pragma unroll
    for (int j = 0; j < 2; ++j)
#pragma unroll
      for (int r = 0; r < 4; ++r) {
        const int gm = (tm << 6) + wm + i * 16 + (fs << 2) + r;
        const int gn = (tn << 6) + wn + j * 16 + fr;
        const size_t idx = (size_t)gm * N + gn;
        const size_t sidx = (size_t)gm * N + swzc(gm, gn);
        const float t = acc[i][j][r];
        if (c.role == 0) {
          float v = c.alpha * t;
          if (c.E0) v = fmaf(c.c0, c.E0[idx], v);
          if (c.E1) v = fmaf(c.c1v, c.E1[idx], v);
          if (c.of) c.of[idx] = v;
          if (c.oh) {
            u16 h, l;
            splitbf(v, h, l);
            c.oh[sidx] = h;
            if (c.ol) c.ol[sidx] = l;
          }
        } else {
          const float e = BETA * (t - c.E0[idx]);  // e3
          c.of2[idx] = e;
          u16 h, l;
          splitbf(e, h, l);
          c.oh[sidx] = h;
          c.ol[sidx] = l;
          const float dv = -LR * e;                // d3 seed
          c.of3[idx] = dv;
          splitbf(dv, h, l);
          c.oh2[sidx] = h;
          c.ol2[sidx] = l;
        }
      }
}

// ---------------------------------------------------------------------------
// merged straight split: fp32 row-major -> swizzled bf16 hi (+lo)
// ---------------------------------------------------------------------------
struct SCfg {
  const float* src;
  u16 *oh, *ol;
  int nblk, cshift;  // nblk = ngrp/256
};

__global__ void split_s_m(SCfg ca, SCfg cb, SCfg cc, int nb0, int nb1) {
  SCfg c;
  int b = blockIdx.x;
  if (b < nb0) c = ca;
  else if (b < nb1) { c = cb; b -= nb0; }
  else { c = cc; b -= nb1; }
  const int g = b * 256 + threadIdx.x;
  const int i = g * 8;
  const int r = i >> c.cshift;
  const int ci = i & ((1 << c.cshift) - 1);
  const float4 a = *(const float4*)(c.src + i);
  const float4 b4 = *(const float4*)(c.src + i + 4);
  const float v[8] = {a.x, a.y, a.z, a.w, b4.x, b4.y, b4.z, b4.w};
  u16 h[8], l[8];
#pragma unroll
  for (int j = 0; j < 8; ++j) splitbf(v[j], h[j], l[j]);
  const size_t dst = ((size_t)r << c.cshift) + (ci & ~63) +
                     ((((ci >> 3) & 7) ^ (r & 7)) << 3);
  *(uint4*)(c.oh + dst) = make_uint4(pack2(h[0], h[1]), pack2(h[2], h[3]),
                                     pack2(h[4], h[5]), pack2(h[6], h[7]));
  if (c.ol)
    *(uint4*)(c.ol + dst) = make_uint4(pack2(l[0], l[1]), pack2(l[2], l[3]),
                                       pack2(l[4], l[5]), pack2(l[6], l[7]));
}

// ---------------------------------------------------------------------------
// merged transpose split: out[cc][rr] = split(a[rr][cc] (+ b[rr][cc]))
// in R x C row-major; out swizzled [C][R]; blocks per cfg = (C/64)*(R/64)
// ---------------------------------------------------------------------------
struct TCfg {
  const float *a, *b;
  u16 *oh, *ol;
  int R, C, nbx, op;
};

__global__ __launch_bounds__(256) void split_t_m(TCfg c0, TCfg c1, TCfg c2,
                                                 TCfg c3, TCfg c4, int4 nb) {
  __shared__ float tile[64][65];
  TCfg c;
  int b = blockIdx.x;
  if (b < nb.x) c = c0;
  else if (b < nb.y) { c = c1; b -= nb.x; }
  else if (b < nb.z) { c = c2; b -= nb.y; }
  else if (b < nb.w) { c = c3; b -= nb.z; }
  else { c = c4; b -= nb.w; }
  const int tid = threadIdx.x;
  const int cb0 = (b % c.nbx) << 6, r0 = (b / c.nbx) << 6;
#pragma unroll
  for (int q = 0; q < 16; ++q) {
    const int i = q * 256 + tid;
    const int r = i >> 6, cc = i & 63;
    const size_t src = (size_t)(r0 + r) * c.C + cb0 + cc;
    float v = c.a[src];
    if (c.op == 1) v += c.b[src];
    tile[r][cc] = v;
  }
  __syncthreads();
#pragma unroll
  for (int q = 0; q < 2; ++q) {
    const int g = q * 256 + tid;
    const int oc = g >> 3, os = g & 7;
    u16 h[8], l[8];
#pragma unroll
    for (int j = 0; j < 8; ++j) splitbf(tile[os * 8 + j][oc], h[j], l[j]);
    const int orow = cb0 + oc;
    const size_t dst = (size_t)orow * c.R + r0 + ((os ^ (orow & 7)) << 3);
    *(uint4*)(c.oh + dst) = make_uint4(pack2(h[0], h[1]), pack2(h[2], h[3]),
                                       pack2(h[4], h[5]), pack2(h[6], h[7]));
    *(uint4*)(c.ol + dst) = make_uint4(pack2(l[0], l[1]), pack2(l[2], l[3]),
                                       pack2(l[4], l[5]), pack2(l[6], l[7]));
  }
}

// ---------------------------------------------------------------------------
__global__ void loss_sq(const float* __restrict__ e, float* __restrict__ partials,
                        int n) {
  __shared__ float red[256];
  float s = 0.f;
  for (int i = blockIdx.x * 256 + threadIdx.x; i < n; i += gridDim.x * 256)
    s = fmaf(e[i], e[i], s);
  red[threadIdx.x] = s;
  __syncthreads();
  for (int off = 128; off > 0; off >>= 1) {
    if (threadIdx.x < off) red[threadIdx.x] += red[threadIdx.x + off];
    __syncthreads();
  }
  if (threadIdx.x == 0) partials[blockIdx.x] = red[0];
}

__global__ void loss_final(const float* __restrict__ partials,
                           float* __restrict__ o, int np, float inv) {
  __shared__ float red[256];
  float s = 0.f;
  for (int i = threadIdx.x; i < np; i += 256) s += partials[i];
  red[threadIdx.x] = s;
  __syncthreads();
  for (int off = 128; off > 0; off >>= 1) {
    if (threadIdx.x < off) red[threadIdx.x] += red[threadIdx.x + off];
    __syncthreads();
  }
  if (threadIdx.x == 0) o[0] = red[0] * inv;
}

}  // namespace

extern "C" void kernel_launch(void* const* d_in, const int* in_sizes, int n_in,
                              void* d_out, int out_size, void* d_ws, size_t ws_size,
                              hipStream_t stream) {
  const float* x  = (const float*)d_in[0];   // 1024 x 1024
  const float* y  = (const float*)d_in[1];   // 1024 x 512
  const float* W0 = (const float*)d_in[2];   // 1024 x 1024
  const float* W1 = (const float*)d_in[3];   // 1024 x 1024
  const float* W2 = (const float*)d_in[4];   // 1024 x 512
  float* out = (float*)d_out;

  const size_t M1 = 1u << 20;
  const size_t M5 = 1u << 19;

  char* wp = (char*)d_ws;
  auto F = [&](size_t n) { float* p = (float*)wp; wp += n * 4; return p; };
  auto U = [&](size_t n) { u16* p = (u16*)wp; wp += n * 2; return p; };

  float* c1f = F(M1);
  float* c2f = F(M1);
  float* e3f = F(M5);
  float* d1f[2] = {F(M1), F(M1)};
  float* d2f[2] = {F(M1), F(M1)};
  float* d3f[2] = {F(M5), F(M5)};
  float* r2f = F(M1);
  float* r3f = F(M5);
  float* lp = F(1024);

  u16 *xh = U(M1), *xl = U(M1);
  u16 *xth = U(M1), *xtl = U(M1);
  u16 *W0th = U(M1), *W0tl = U(M1);
  u16 *W1h = U(M1), *W1l = U(M1);
  u16 *W1th = U(M1), *W1tl = U(M1);
  u16 *W2h = U(M5), *W2l = U(M5);
  u16 *W2th = U(M5), *W2tl = U(M5);
  u16 *G1h = U(M1), *G2h = U(M1), *Ph = U(M5);
  u16 *c1h = U(M1), *c1l = U(M1);
  u16 *c2h = U(M1), *c2l = U(M1);
  u16 *e3h = U(M5), *e3l = U(M5);
  u16 *d1h[2] = {U(M1), U(M1)}, *d1l[2] = {U(M1), U(M1)};
  u16 *d2h[2] = {U(M1), U(M1)}, *d2l[2] = {U(M1), U(M1)};
  u16 *d3h[2] = {U(M5), U(M5)}, *d3l[2] = {U(M5), U(M5)};
  u16 *s1th = U(M1), *s1tl = U(M1);
  u16 *s2th = U(M1), *s2tl = U(M1);
  u16 *r1th = U(M1), *r1tl = U(M1);
  u16 *r2th = U(M1), *r2tl = U(M1);
  u16 *r3th = U(M5), *r3tl = U(M5);

  float* ep0 = out;
  float* ep1 = out + M1;
  float* ep2 = out + 2 * M1;
  float* lossp = out + 2 * M1 + M5;

  const dim3 blk(256);
  const float IB = -1.0f / BETA;

  auto R = [](const u16* ah, const u16* al, const u16* bh, const u16* bl,
              int kw) {
    Region r;
    r.Ah = ah; r.Al = al; r.Bh = bh; r.Bl = bl;
    r.kw = kw; r.nks = kw >> 6;
    return r;
  };
  auto mk = [&](Region r0, float alpha, int N, const float* E0,
                const float* E1, float c0, float c1v, float* of, u16* oh,
                u16* ol) {
    GemmP p{};
    p.rg[0] = r0;
    p.rg[1] = r0; p.rg[1].nks = 0;
    p.rg[2] = r0; p.rg[2].nks = 0;
    p.E0 = E0; p.E1 = E1;
    p.of = of; p.of2 = nullptr; p.of3 = nullptr;
    p.oh = oh; p.ol = ol; p.oh2 = nullptr; p.ol2 = nullptr;
    p.alpha = alpha; p.c0 = c0; p.c1v = c1v;
    p.N = N; p.ntn = N >> 6; p.role = 0;
    return p;
  };

  // ---- L1: straight splits (x, W1, W2) ----
  {
    SCfg a{x, xh, xl, 512, 10};
    SCfg b{W1, W1h, W1l, 512, 10};
    SCfg c{W2, W2h, W2l, 256, 9};
    split_s_m<<<1280, blk, 0, stream>>>(a, b, c, 512, 1024);
  }
  // ---- L2: transpose splits (x, W0, W1, W2) ----
  {
    TCfg t0{x, nullptr, xth, xtl, 1024, 1024, 16, 0};
    TCfg t1{W0, nullptr, W0th, W0tl, 1024, 1024, 16, 0};
    TCfg t2{W1, nullptr, W1th, W1tl, 1024, 1024, 16, 0};
    TCfg t3{W2, nullptr, W2th, W2tl, 1024, 512, 8, 0};
    split_t_m<<<896, blk, 0, stream>>>(t0, t1, t2, t3, t3,
                                       make_int4(256, 512, 768, 896));
  }
  // ---- L3: precompute {-G1, -G2, P} + c1 (NP3) ----
  {
    GemmP g1 = mk(R(W1h, W1l, W1h, W1l, 1024), -1.f, 1024, nullptr, nullptr,
                  0.f, 0.f, nullptr, G1h, nullptr);
    GemmP g2 = mk(R(W2h, W2l, W2h, W2l, 512), -1.f, 1024, nullptr, nullptr,
                  0.f, 0.f, nullptr, G2h, nullptr);
    GemmP pp = mk(R(W1h, W1l, W2th, W2tl, 1024), 1.f, 512, nullptr, nullptr,
                  0.f, 0.f, nullptr, Ph, nullptr);
    GemmP c1 = mk(R(xh, xl, W0th, W0tl, 1024), 1.f, 1024, nullptr, nullptr,
                  0.f, 0.f, c1f, c1h, c1l);
    gemm_g<3><<<896, blk, 0, stream>>>(g1, g2, pp, c1, 256, 512, 640);
  }
  // ---- L4: c2 = c1@W1 (NP3) ----
  {
    GemmP c2 = mk(R(c1h, c1l, W1th, W1tl, 1024), 1.f, 1024, nullptr, nullptr,
                  0.f, 0.f, c2f, c2h, c2l);
    gemm_g<3><<<256, blk, 0, stream>>>(c2, c2, c2, c2, 256, 256, 256);
  }
  // ---- L5: role1 -> e3, d3 seed (NP3) ----
  {
    GemmP p = mk(R(c2h, c2l, W2th, W2tl, 1024), 1.f, 512, y, nullptr, 0.f,
                 0.f, nullptr, e3h, e3l);
    p.role = 1;
    p.of2 = e3f;
    p.of3 = d3f[0];
    p.oh2 = d3h[0];
    p.ol2 = d3l[0];
    gemm_g<3><<<128, blk, 0, stream>>>(p, p, p, p, 128, 128, 128);
  }
  // ---- L6: iter0 {d2 = -lr*e3@W2^T, d1 = -lr*e3@P^T} (NP2) ----
  {
    GemmP pd2 = mk(R(e3h, e3l, W2h, nullptr, 512), -LR, 1024, nullptr,
                   nullptr, 0.f, 0.f, d2f[0], d2h[0], d2l[0]);
    GemmP pd1 = mk(R(e3h, e3l, Ph, nullptr, 512), -LR, 1024, nullptr, nullptr,
                   0.f, 0.f, d1f[0], d1h[0], d1l[0]);
    gemm_g<2><<<512, blk, 0, stream>>>(pd2, pd1, pd1, pd1, 256, 512, 512);
  }
  // ---- iterations 1..19: one launch each ----
  for (int t = 1; t < 20; ++t) {
    const int sp = (t - 1) & 1, dp = t & 1;
    GemmP A = mk(R(d2h[sp], d2l[sp], W1h, nullptr, 1024), LR, 1024, d1f[sp],
                 nullptr, 1.f - LR, 0.f, d1f[dp], d1h[dp], d1l[dp]);
    A.rg[1] = R(d1h[sp], d1l[sp], G1h, nullptr, 1024);
    GemmP B = mk(R(d1h[sp], d1l[sp], W1th, nullptr, 1024), LR, 1024, d2f[sp],
                 nullptr, 1.f - LR, 0.f, d2f[dp], d2h[dp], d2l[dp]);
    B.rg[1] = R(d3h[sp], d3l[sp], W2h, nullptr, 512);
    B.rg[2] = R(d2h[sp], d2l[sp], G2h, nullptr, 1024);
    GemmP C = mk(R(d2h[sp], d2l[sp], W2th, nullptr, 1024), LR, 512, d3f[sp],
                 e3f, 1.f - LR - LR * BETA, -LR, d3f[dp], d3h[dp], d3l[dp]);
    gemm_g<2><<<640, blk, 0, stream>>>(A, B, C, C, 256, 512, 640);
  }
  // ---- final residuals: r2* = d2 - d1@W1 ; r3* = d3 - d2@W2 ----
  {
    GemmP p2 = mk(R(d1h[1], d1l[1], W1th, nullptr, 1024), -1.f, 1024, d2f[1],
                  nullptr, 1.f, 0.f, r2f, nullptr, nullptr);
    GemmP p3 = mk(R(d2h[1], d2l[1], W2th, nullptr, 1024), -1.f, 512, d3f[1],
                  nullptr, 1.f, 0.f, r3f, nullptr, nullptr);
    gemm_g<2><<<384, blk, 0, stream>>>(p2, p3, p3, p3, 256, 384, 384);
  }
  // ---- transposed splits for ep ----
  {
    TCfg t0{c1f, d1f[1], s1th, s1tl, 1024, 1024, 16, 1};
    TCfg t1{c2f, d2f[1], s2th, s2tl, 1024, 1024, 16, 1};
    TCfg t2{d1f[1], nullptr, r1th, r1tl, 1024, 1024, 16, 0};
    TCfg t3{r2f, nullptr, r2th, r2tl, 1024, 1024, 16, 0};
    TCfg t4{r3f, nullptr, r3th, r3tl, 1024, 512, 8, 0};
    split_t_m<<<1152, blk, 0, stream>>>(t0, t1, t2, t3, t4,
                                        make_int4(256, 512, 768, 1024));
  }
  // ---- EP grads (NP3): ep_i = -(1/b) * A^T B ----
  {
    GemmP p0 = mk(R(xth, xtl, r1th, r1tl, 1024), IB, 1024, nullptr, nullptr,
                  0.f, 0.f, ep0, nullptr, nullptr);
    GemmP p1 = mk(R(s1th, s1tl, r2th, r2tl, 1024), IB, 1024, nullptr, nullptr,
                  0.f, 0.f, ep1, nullptr, nullptr);
    GemmP p2 = mk(R(s2th, s2tl, r3th, r3tl, 1024), IB, 512, nullptr, nullptr,
                  0.f, 0.f, ep2, nullptr, nullptr);
    gemm_g<3><<<640, blk, 0, stream>>>(p0, p1, p2, p2, 256, 512, 640);
  }
  // ---- loss = mean(e3^2)/beta^2 ----
  loss_sq<<<512, blk, 0, stream>>>(e3f, lp, (int)M5);
  loss_final<<<1, blk, 0, stream>>>(lp, lossp, 512,
                                    1.0f / (BETA * BETA * (float)M5));
}

// Round 6
// 988.414 us; speedup vs baseline: 1.6017x; 1.6017x over previous
//
#include <hip/hip_runtime.h>

// EP model, deviation-space formulation, split-bf16 MFMA, global_load_lds
// staging with swizzle baked into global operand storage. R4 structure
// (proven) + XCD-chunked block swizzle (T1/m204) for per-XCD L2 residency.
//
// s_k = c_k + d_k with c the free forward chain (exact fixed point).
// iter0: e3 = beta*(c3-y); d3 = -lr*e3; d2 = -lr*(e3@W2^T); d1 = d2@W1^T
// iters 1..19:
//   r2 = d2 - d1@W1 ; r3 = d3 - d2@W2
//   d3 = (1-lr*beta)*d3 - lr*r3 - lr*e3
//   d1 = (1-lr)*d1 + lr*(r2@W1^T) ; d2 = d2 - lr*r2 + lr*(r3@W2^T)
// final: r2* = d2 - d1@W1 ; r3* = d3 - d2@W2
// ep0 = -(1/b) x^T d1 ; ep1 = -(1/b) s1^T r2* ; ep2 = -(1/b) s2^T r3*
// loss = mean(e3^2)/beta^2

typedef float f32x4 __attribute__((ext_vector_type(4)));
typedef __bf16 bf16x8 __attribute__((ext_vector_type(8)));
typedef unsigned short u16;
typedef unsigned int u32;

namespace {

constexpr float LR = 0.5f;
constexpr float BETA = 1e-3f;

__device__ inline void splitbf(float v, u16& h, u16& l) {
  __bf16 hb = (__bf16)v;
  float hf = (float)hb;
  __bf16 lb = (__bf16)(v - hf);
  h = __builtin_bit_cast(u16, hb);
  l = __builtin_bit_cast(u16, lb);
}
__device__ inline u32 pack2(u16 a, u16 b) { return (u32)a | ((u32)b << 16); }

__device__ inline f32x4 MF(bf16x8 a, bf16x8 b, f32x4 c) {
  return __builtin_amdgcn_mfma_f32_16x16x32_bf16(a, b, c, 0, 0, 0);
}

// swizzled column index: 16B chunk within 128B window permuted by row&7
__device__ inline int swzc(int row, int col) {
  return (col & ~63) | ((((col >> 3) & 7) ^ (row & 7)) << 3) | (col & 7);
}

struct GemmP {
  const u16 *Ah, *Al, *Bh, *Bl;
  const float *E0, *E1;
  float *of, *of2, *of3;
  u16 *oh, *ol;
  float alpha, c0, c1v;
  int N, K, ntn, role;
};

// ---------------------------------------------------------------------------
// NT MFMA GEMM, 64x64 tile, BK=64, 4 waves, global_load_lds staging.
// C[m,n] = sum_k A[m,k]*B[n,k];  NP=2: (Ah+Al)*Bh ; NP=3: +Ah*Bl
// role 0: v = alpha*S + c0*E0 + c1v*E1 -> of / (oh,ol swizzled)
// role 1: c3=S -> of; e3=beta*(S-E0) -> of2 + (oh,ol); of3 = -lr*e3
// role 2: r3 = E0 - S -> (oh,ol); of = (1-lr*b)*E0 - lr*r3 - lr*E1
// Block index is XCD-chunk swizzled per segment (seg sizes are %8==0):
// XCD k owns a contiguous range of tile indices -> its row-sweep's B-panel
// (<=2MB) + A-rows (<=1MB) stay resident in the 4MB per-XCD L2.
// ---------------------------------------------------------------------------
template <int NP>
__global__ __launch_bounds__(256) void gemm_g(GemmP ca, GemmP cb, GemmP cc,
                                              int nb0, int nb01) {
  constexpr int NARR = NP + 1;   // Ah, Al, Bh, (Bl)
  constexpr int NCH = NARR * 2;  // 1KB wave-loads per wave per k-step
  __shared__ u16 lds[2][NARR][64 * 64];
  GemmP c;
  int b = blockIdx.x;
  int seg;
  if (b < nb0) { c = ca; seg = nb0; }
  else if (b < nb01) { c = cb; b -= nb0; seg = nb01 - nb0; }
  else { c = cc; b -= nb01; seg = (int)gridDim.x - nb01; }
  // XCD-chunked bijective swizzle (requires seg % 8 == 0)
  b = (b & 7) * (seg >> 3) + (b >> 3);
  const int tm = b / c.ntn, tn = b % c.ntn;
  const int tid = threadIdx.x, lane = tid & 63, w = tid >> 6;
  const int K = c.K;

  // ---- staging setup: per wave NCH 1KB loads (8 rows x 128B each) ----
  const char* gq[NCH];
  int loff[NCH];  // wave-uniform byte offset within one lds buffer
  {
    const u16* bases[4] = {c.Ah, c.Al, c.Bh, c.Bl};
#pragma unroll
    for (int q = 0; q < NCH; ++q) {
      const int kb = q * 4 + w;          // 0 .. NARR*8-1
      const int a = kb >> 3, rb = kb & 7;
      const int row0 = (a < 2 ? tm : tn) << 6;
      gq[q] = (const char*)bases[a] +
              (((size_t)(row0 + rb * 8 + (lane >> 3)) * K) << 1) +
              ((lane & 7) << 4);
      loff[q] = a * 8192 + rb * 1024;
    }
  }

  // ---- fragment read byte offsets (same XOR as storage swizzle) ----
  const int wm = (w >> 1) << 5, wn = (w & 1) << 5;
  const int fr = lane & 15, fs = lane >> 4;
  int aoff[2][2], boff[2][2];
#pragma unroll
  for (int i = 0; i < 2; ++i)
#pragma unroll
    for (int kk = 0; kk < 2; ++kk) {
      const int ra = wm + i * 16 + fr;
      aoff[i][kk] = ra * 128 + ((((kk << 2) + fs) ^ (ra & 7)) << 4);
      const int rb2 = wn + i * 16 + fr;
      boff[i][kk] = rb2 * 128 + ((((kk << 2) + fs) ^ (rb2 & 7)) << 4);
    }

  auto stage = [&](int s, int buf) {
    char* lb = (char*)&lds[buf][0][0];
#pragma unroll
    for (int q = 0; q < NCH; ++q)
      __builtin_amdgcn_global_load_lds(
          (const __attribute__((address_space(1))) unsigned int*)(gq[q] +
                                                                  (size_t)s * 128),
          (__attribute__((address_space(3))) unsigned int*)(lb + loff[q]), 16,
          0, 0);
  };

  f32x4 acc[2][2] = {};
  const int nk = K >> 6;

  stage(0, 0);
  __syncthreads();
  int cur = 0;
  for (int s = 0; s < nk; ++s) {
    if (s + 1 < nk) stage(s + 1, cur ^ 1);
    const char* rb = (const char*)&lds[cur][0][0];
    bf16x8 ah[2][2], al[2][2], bh[2][2], bl[2][2];
#pragma unroll
    for (int i = 0; i < 2; ++i)
#pragma unroll
      for (int kk = 0; kk < 2; ++kk) {
        ah[i][kk] = *(const bf16x8*)(rb + aoff[i][kk]);
        al[i][kk] = *(const bf16x8*)(rb + 8192 + aoff[i][kk]);
        bh[i][kk] = *(const bf16x8*)(rb + 16384 + boff[i][kk]);
        if (NP == 3) bl[i][kk] = *(const bf16x8*)(rb + 24576 + boff[i][kk]);
      }
#pragma unroll
    for (int kk = 0; kk < 2; ++kk)
#pragma unroll
      for (int i = 0; i < 2; ++i)
#pragma unroll
        for (int j = 0; j < 2; ++j) {
          acc[i][j] = MF(ah[i][kk], bh[j][kk], acc[i][j]);
          acc[i][j] = MF(al[i][kk], bh[j][kk], acc[i][j]);
          if (NP == 3) acc[i][j] = MF(ah[i][kk], bl[j][kk], acc[i][j]);
        }
    __syncthreads();  // drains vmcnt (stage) + lgkm; flips buffer
    cur ^= 1;
  }

  // ---- fused epilogue; C/D layout: col=lane&15, row=(lane>>4)*4+reg ----
  const int N = c.N;
#pragma unroll
  for (int i = 0; i < 2; ++i)
#pragma unroll
    for (int j = 0; j < 2; ++j)
#pragma unroll
      for (int r = 0; r < 4; ++r) {
        const int gm = (tm << 6) + wm + i * 16 + (fs << 2) + r;
        const int gn = (tn << 6) + wn + j * 16 + fr;
        const size_t idx = (size_t)gm * N + gn;
        const size_t sidx = (size_t)gm * N + swzc(gm, gn);
        const float t = acc[i][j][r];
        if (c.role == 0) {
          float v = c.alpha * t;
          if (c.E0) v = fmaf(c.c0, c.E0[idx], v);
          if (c.E1) v = fmaf(c.c1v, c.E1[idx], v);
          if (c.of) c.of[idx] = v;
          if (c.oh) {
            u16 h, l;
            splitbf(v, h, l);
            c.oh[sidx] = h;
            c.ol[sidx] = l;
          }
        } else if (c.role == 1) {
          c.of[idx] = t;                           // c3
          const float e = BETA * (t - c.E0[idx]);  // e3
          c.of2[idx] = e;
          u16 h, l;
          splitbf(e, h, l);
          c.oh[sidx] = h;
          c.ol[sidx] = l;
          c.of3[idx] = -LR * e;                    // d3 seed
        } else {
          const float d3o = c.E0[idx];
          const float r3 = d3o - t;
          u16 h, l;
          splitbf(r3, h, l);
          c.oh[sidx] = h;
          c.ol[sidx] = l;
          c.of[idx] = (1.0f - LR * BETA) * d3o - LR * r3 - LR * c.E1[idx];
        }
      }
}

// ---------------------------------------------------------------------------
// straight split: fp32 row-major -> swizzled bf16 hi (+lo); cshift=log2(cols)
// ---------------------------------------------------------------------------
template <bool WLO>
__global__ void split_s(const float* __restrict__ src, u16* __restrict__ oh,
                        u16* __restrict__ ol, int ngrp, int cshift) {
  const int g = blockIdx.x * blockDim.x + threadIdx.x;
  if (g >= ngrp) return;
  const int i = g * 8;
  const int r = i >> cshift;
  const int ci = i & ((1 << cshift) - 1);  // chunk-aligned column
  const float4 a = *(const float4*)(src + i);
  const float4 b = *(const float4*)(src + i + 4);
  const float v[8] = {a.x, a.y, a.z, a.w, b.x, b.y, b.z, b.w};
  u16 h[8], l[8];
#pragma unroll
  for (int j = 0; j < 8; ++j) splitbf(v[j], h[j], l[j]);
  const size_t dst = ((size_t)r << cshift) + (ci & ~63) +
                     ((((ci >> 3) & 7) ^ (r & 7)) << 3);
  *(uint4*)(oh + dst) = make_uint4(pack2(h[0], h[1]), pack2(h[2], h[3]),
                                   pack2(h[4], h[5]), pack2(h[6], h[7]));
  if (WLO)
    *(uint4*)(ol + dst) = make_uint4(pack2(l[0], l[1]), pack2(l[2], l[3]),
                                     pack2(l[4], l[5]), pack2(l[6], l[7]));
}

// ---------------------------------------------------------------------------
// transpose split: out[c][r] = split(a[r][c] (+ b[r][c])); out swizzled.
// in R x C row-major, grid (C/64, R/64)
// ---------------------------------------------------------------------------
template <int OP>  // 0: a, 1: a+b
__global__ __launch_bounds__(256) void split_t(const float* __restrict__ a,
                                               const float* __restrict__ b,
                                               u16* __restrict__ oh,
                                               u16* __restrict__ ol, int R,
                                               int C) {
  __shared__ float tile[64][65];
  const int tid = threadIdx.x;
  const int c0 = blockIdx.x << 6, r0 = blockIdx.y << 6;
#pragma unroll
  for (int q = 0; q < 16; ++q) {
    const int i = q * 256 + tid;
    const int r = i >> 6, cc = i & 63;
    const size_t src = (size_t)(r0 + r) * C + c0 + cc;
    float v = a[src];
    if (OP == 1) v += b[src];
    tile[r][cc] = v;
  }
  __syncthreads();
#pragma unroll
  for (int q = 0; q < 2; ++q) {
    const int g = q * 256 + tid;
    const int oc = g >> 3, os = g & 7;  // out-row c0+oc, chunk os of window r0
    u16 h[8], l[8];
#pragma unroll
    for (int j = 0; j < 8; ++j) splitbf(tile[os * 8 + j][oc], h[j], l[j]);
    const int orow = c0 + oc;
    const size_t dst = (size_t)orow * R + r0 + ((os ^ (orow & 7)) << 3);
    *(uint4*)(oh + dst) = make_uint4(pack2(h[0], h[1]), pack2(h[2], h[3]),
                                     pack2(h[4], h[5]), pack2(h[6], h[7]));
    *(uint4*)(ol + dst) = make_uint4(pack2(l[0], l[1]), pack2(l[2], l[3]),
                                     pack2(l[4], l[5]), pack2(l[6], l[7]));
  }
}

// ---------------------------------------------------------------------------
__global__ void loss_sq(const float* __restrict__ e, float* __restrict__ partials,
                        int n) {
  __shared__ float red[256];
  float s = 0.f;
  for (int i = blockIdx.x * 256 + threadIdx.x; i < n; i += gridDim.x * 256)
    s = fmaf(e[i], e[i], s);
  red[threadIdx.x] = s;
  __syncthreads();
  for (int off = 128; off > 0; off >>= 1) {
    if (threadIdx.x < off) red[threadIdx.x] += red[threadIdx.x + off];
    __syncthreads();
  }
  if (threadIdx.x == 0) partials[blockIdx.x] = red[0];
}

__global__ void loss_final(const float* __restrict__ partials,
                           float* __restrict__ o, int np, float inv) {
  __shared__ float red[256];
  float s = 0.f;
  for (int i = threadIdx.x; i < np; i += 256) s += partials[i];
  red[threadIdx.x] = s;
  __syncthreads();
  for (int off = 128; off > 0; off >>= 1) {
    if (threadIdx.x < off) red[threadIdx.x] += red[threadIdx.x + off];
    __syncthreads();
  }
  if (threadIdx.x == 0) o[0] = red[0] * inv;
}

}  // namespace

extern "C" void kernel_launch(void* const* d_in, const int* in_sizes, int n_in,
                              void* d_out, int out_size, void* d_ws, size_t ws_size,
                              hipStream_t stream) {
  const float* x  = (const float*)d_in[0];   // 1024 x 1024
  const float* y  = (const float*)d_in[1];   // 1024 x 512
  const float* W0 = (const float*)d_in[2];   // 1024 x 1024
  const float* W1 = (const float*)d_in[3];   // 1024 x 1024
  const float* W2 = (const float*)d_in[4];   // 1024 x 512
  float* out = (float*)d_out;

  const size_t M1 = 1u << 20;
  const size_t M5 = 1u << 19;

  char* wp = (char*)d_ws;
  auto F = [&](size_t n) { float* p = (float*)wp; wp += n * 4; return p; };
  auto U = [&](size_t n) { u16* p = (u16*)wp; wp += n * 2; return p; };

  float* c1 = F(M1);  float* c2 = F(M1);  float* c3 = F(M5);
  float* e3 = F(M5);  float* d1 = F(M1);  float* d2 = F(M1);
  float* d3 = F(M5);  float* r2f = F(M1); float* r3f = F(M5);
  float* lp = F(1024);

  u16* xh = U(M1);   u16* xl = U(M1);     // reused as r2th/r2tl at end
  u16* xth = U(M1);  u16* xtl = U(M1);
  u16* W0th = U(M1); u16* W0tl = U(M1);   // reused as r1th/r1tl at end
  u16* W1h = U(M1);
  u16* W1th = U(M1); u16* W1tl = U(M1);
  u16* W2h = U(M5);
  u16* W2th = U(M5); u16* W2tl = U(M5);
  u16* c1h = U(M1);  u16* c1l = U(M1);    // reused as s1th/s1tl at end
  u16* c2h = U(M1);  u16* c2l = U(M1);    // reused as s2th/s2tl at end
  u16* d1h = U(M1);  u16* d1l = U(M1);
  u16* d2h = U(M1);  u16* d2l = U(M1);
  u16* e3h = U(M5);  u16* e3l = U(M5);    // reused as r3th/r3tl at end
  u16* r2h = U(M1);  u16* r2l = U(M1);
  u16* r3h = U(M5);  u16* r3l = U(M5);

  float* ep0 = out;
  float* ep1 = out + M1;
  float* ep2 = out + 2 * M1;
  float* lossp = out + 2 * M1 + M5;

  const dim3 blk(256);
  const float IB = -1.0f / BETA;

  auto mk = [](const u16* Ah, const u16* Al, const u16* Bh, const u16* Bl,
               int N, int K, int role, float alpha, float c0, float c1v,
               const float* E0, const float* E1, float* of, u16* oh, u16* ol,
               float* of2, float* of3) {
    GemmP p;
    p.Ah = Ah; p.Al = Al; p.Bh = Bh; p.Bl = Bl;
    p.E0 = E0; p.E1 = E1; p.of = of; p.of2 = of2; p.of3 = of3;
    p.oh = oh; p.ol = ol; p.alpha = alpha; p.c0 = c0; p.c1v = c1v;
    p.N = N; p.K = K; p.ntn = N >> 6; p.role = role;
    return p;
  };

  // ---- one-time operand splits (swizzled storage) ----
  split_s<true><<<512, blk, 0, stream>>>(x, xh, xl, (int)(M1 / 8), 10);
  split_s<false><<<512, blk, 0, stream>>>(W1, W1h, nullptr, (int)(M1 / 8), 10);
  split_s<false><<<256, blk, 0, stream>>>(W2, W2h, nullptr, (int)(M5 / 8), 9);
  split_t<0><<<dim3(16, 16), blk, 0, stream>>>(x, nullptr, xth, xtl, 1024, 1024);
  split_t<0><<<dim3(16, 16), blk, 0, stream>>>(W0, nullptr, W0th, W0tl, 1024, 1024);
  split_t<0><<<dim3(16, 16), blk, 0, stream>>>(W1, nullptr, W1th, W1tl, 1024, 1024);
  split_t<0><<<dim3(8, 16), blk, 0, stream>>>(W2, nullptr, W2th, W2tl, 1024, 512);

  // ---- forward chain (3-product, fp32-parity) ----
  {
    GemmP p = mk(xh, xl, W0th, W0tl, 1024, 1024, 0, 1.f, 0.f, 0.f,
                 nullptr, nullptr, c1, c1h, c1l, nullptr, nullptr);
    gemm_g<3><<<256, blk, 0, stream>>>(p, p, p, 256, 256);
  }
  {
    GemmP p = mk(c1h, c1l, W1th, W1tl, 1024, 1024, 0, 1.f, 0.f, 0.f,
                 nullptr, nullptr, c2, c2h, c2l, nullptr, nullptr);
    gemm_g<3><<<256, blk, 0, stream>>>(p, p, p, 256, 256);
  }
  {  // role 1: c3, e3 (+split), d3 = -lr*e3
    GemmP p = mk(c2h, c2l, W2th, W2tl, 512, 1024, 1, 1.f, 0.f, 0.f,
                 y, nullptr, c3, e3h, e3l, e3, d3);
    gemm_g<3><<<128, blk, 0, stream>>>(p, p, p, 128, 128);
  }
  loss_sq<<<512, blk, 0, stream>>>(e3, lp, (int)M5);
  loss_final<<<1, blk, 0, stream>>>(lp, lossp, 512,
                                    1.0f / (BETA * BETA * (float)M5));

  // ---- iter 0 (coupled; collapses in d-space) ----
  {  // d2 = -lr * (e3 @ W2^T)
    GemmP p = mk(e3h, e3l, W2h, nullptr, 1024, 512, 0, -LR, 0.f, 0.f,
                 nullptr, nullptr, d2, d2h, d2l, nullptr, nullptr);
    gemm_g<2><<<256, blk, 0, stream>>>(p, p, p, 256, 256);
  }
  {  // d1 = d2 @ W1^T
    GemmP p = mk(d2h, d2l, W1h, nullptr, 1024, 1024, 0, 1.f, 0.f, 0.f,
                 nullptr, nullptr, d1, d1h, d1l, nullptr, nullptr);
    gemm_g<2><<<256, blk, 0, stream>>>(p, p, p, 256, 256);
  }

  // ---- iterations 1..19 ----
  for (int it = 1; it < 20; ++it) {
    GemmP pa = mk(d1h, d1l, W1th, nullptr, 1024, 1024, 0, -1.f, 1.f, 0.f,
                  d2, nullptr, r2f, r2h, r2l, nullptr, nullptr);
    GemmP pb = mk(d2h, d2l, W2th, nullptr, 512, 1024, 2, 0.f, 0.f, 0.f,
                  d3, e3, d3, r3h, r3l, nullptr, nullptr);
    gemm_g<2><<<384, blk, 0, stream>>>(pa, pb, pb, 256, 384);
    GemmP pc = mk(r2h, r2l, W1h, nullptr, 1024, 1024, 0, LR, 1.f - LR, 0.f,
                  d1, nullptr, d1, d1h, d1l, nullptr, nullptr);
    GemmP pd = mk(r3h, r3l, W2h, nullptr, 1024, 512, 0, LR, 1.f, -LR,
                  d2, r2f, d2, d2h, d2l, nullptr, nullptr);
    gemm_g<2><<<512, blk, 0, stream>>>(pc, pd, pd, 256, 512);
  }

  // ---- final residuals (fp32 outs only) ----
  {
    GemmP pa = mk(d1h, d1l, W1th, nullptr, 1024, 1024, 0, -1.f, 1.f, 0.f,
                  d2, nullptr, r2f, nullptr, nullptr, nullptr, nullptr);
    GemmP pb = mk(d2h, d2l, W2th, nullptr, 512, 1024, 0, -1.f, 1.f, 0.f,
                  d3, nullptr, r3f, nullptr, nullptr, nullptr, nullptr);
    gemm_g<2><<<384, blk, 0, stream>>>(pa, pb, pb, 256, 384);
  }

  // ---- transposed splits for ep GEMMs (reusing dead regions) ----
  u16 *s1th = c1h, *s1tl = c1l, *s2th = c2h, *s2tl = c2l;
  u16 *r1th = W0th, *r1tl = W0tl, *r2th = xh, *r2tl = xl;
  u16 *r3th = e3h, *r3tl = e3l;
  split_t<1><<<dim3(16, 16), blk, 0, stream>>>(c1, d1, s1th, s1tl, 1024, 1024);
  split_t<1><<<dim3(16, 16), blk, 0, stream>>>(c2, d2, s2th, s2tl, 1024, 1024);
  split_t<0><<<dim3(16, 16), blk, 0, stream>>>(d1, nullptr, r1th, r1tl, 1024, 1024);
  split_t<0><<<dim3(16, 16), blk, 0, stream>>>(r2f, nullptr, r2th, r2tl, 1024, 1024);
  split_t<0><<<dim3(8, 16), blk, 0, stream>>>(r3f, nullptr, r3th, r3tl, 1024, 512);

  // ---- EP weight grads (merged, 3-product): ep = -(1/b) * A^T B ----
  {
    GemmP p0 = mk(xth, xtl, r1th, r1tl, 1024, 1024, 0, IB, 0.f, 0.f,
                  nullptr, nullptr, ep0, nullptr, nullptr, nullptr, nullptr);
    GemmP p1 = mk(s1th, s1tl, r2th, r2tl, 1024, 1024, 0, IB, 0.f, 0.f,
                  nullptr, nullptr, ep1, nullptr, nullptr, nullptr, nullptr);
    GemmP p2 = mk(s2th, s2tl, r3th, r3tl, 512, 1024, 0, IB, 0.f, 0.f,
                  nullptr, nullptr, ep2, nullptr, nullptr, nullptr, nullptr);
    gemm_g<3><<<640, blk, 0, stream>>>(p0, p1, p2, 256, 512);
  }
}